// Round 6
// baseline (273.539 us; speedup 1.0000x reference)
//
#include <hip/hip_runtime.h>

#define B_ 4
#define S_ 4096
#define E_ 1024
#define H_ 128
#define M_ (B_*S_)   // 16384

typedef __attribute__((ext_vector_type(8))) short bf16x8;
typedef __attribute__((ext_vector_type(4))) float f32x4;
typedef __attribute__((ext_vector_type(2))) unsigned int uint2v;

__device__ inline ushort f2bf(float f) {
  union { float f; unsigned u; } v; v.f = f;
  unsigned r = v.u + 0x7fffu + ((v.u >> 16) & 1u);   // RNE
  return (ushort)(r >> 16);
}

// ---- gfx950 cross-lane primitives (register-file, ~2cyc vs ~120cyc ds_bpermute) ----
__device__ inline void pl16sw(unsigned &x, unsigned &y) {
#if __has_builtin(__builtin_amdgcn_permlane16_swap)
  uint2v r = __builtin_amdgcn_permlane16_swap(x, y, false, false);
  x = r.x; y = r.y;
#else
  asm("v_permlane16_swap_b32 %0, %1" : "+v"(x), "+v"(y));
#endif
}
__device__ inline void pl32sw(unsigned &x, unsigned &y) {
#if __has_builtin(__builtin_amdgcn_permlane32_swap)
  uint2v r = __builtin_amdgcn_permlane32_swap(x, y, false, false);
  x = r.x; y = r.y;
#else
  asm("v_permlane32_swap_b32 %0, %1" : "+v"(x), "+v"(y));
#endif
}
// reduce over the 4 quads (lanes {col, col+16, col+32, col+48}); result broadcast to all
__device__ inline float red4max(float v) {
  union { float f; unsigned u; } a, b;
  a.f = v; b.f = v; pl16sw(a.u, b.u);
  float m1 = fmaxf(a.f, b.f);
  a.f = m1; b.f = m1; pl32sw(a.u, b.u);
  return fmaxf(a.f, b.f);
}
__device__ inline float red4sum(float v) {
  union { float f; unsigned u; } a, b;
  a.f = v; b.f = v; pl16sw(a.u, b.u);
  float s1 = a.f + b.f;
  a.f = s1; b.f = s1; pl32sw(a.u, b.u);
  return a.f + b.f;
}
__device__ inline unsigned cvt_pk_bf16(float lo, float hi) {
  unsigned w;
  asm("v_cvt_pk_bf16_f32 %0, %1, %2" : "=v"(w) : "v"(lo), "v"(hi));
  return w;
}

#define GLLDS16(g, l) __builtin_amdgcn_global_load_lds( \
    (const __attribute__((address_space(1))) void*)(g), \
    (__attribute__((address_space(3))) void*)(l), 16, 0, 0)

// ---------- kernel 1: W [1024][128] f32 (x3) -> Wt [3][128][1024] bf16 ----------
__global__ __launch_bounds__(256) void wt_kernel(const float* __restrict__ Wq,
    const float* __restrict__ Wk, const float* __restrict__ Wv,
    ushort* __restrict__ Wt) {
  int bid = blockIdx.x;               // 384 = 3 mats * 4 h-tiles * 32 e-tiles
  int mat = bid >> 7;
  int rem = bid & 127;
  int ht = rem >> 5, et = rem & 31;
  const float* W = mat == 0 ? Wq : (mat == 1 ? Wk : Wv);
  int e0 = et * 32, h0 = ht * 32;
  __shared__ float tl[32][33];
  int t = threadIdx.x;
  int r = t >> 3, c = (t & 7) << 2;
  const float4 f = *(const float4*)(W + (size_t)(e0 + r) * H_ + h0 + c);
  tl[r][c] = f.x; tl[r][c+1] = f.y; tl[r][c+2] = f.z; tl[r][c+3] = f.w;
  __syncthreads();
  ushort4 o;
  o.x = f2bf(tl[c+0][r]); o.y = f2bf(tl[c+1][r]);
  o.z = f2bf(tl[c+2][r]); o.w = f2bf(tl[c+3][r]);
  *(ushort4*)(Wt + ((size_t)mat*H_ + h0 + r) * E_ + e0 + c) = o;
}

// ---------- kernel 2: x f32 -> bf16 (memory-bound) ----------
__global__ __launch_bounds__(256) void xb_kernel(const float* __restrict__ x,
                                                 ushort* __restrict__ xb) {
  size_t i = ((size_t)blockIdx.x * 256 + threadIdx.x) * 8;
  float4 f0 = *(const float4*)(x + i);
  float4 f1 = *(const float4*)(x + i + 4);
  alignas(16) ushort us[8];
  us[0]=f2bf(f0.x); us[1]=f2bf(f0.y); us[2]=f2bf(f0.z); us[3]=f2bf(f0.w);
  us[4]=f2bf(f1.x); us[5]=f2bf(f1.y); us[6]=f2bf(f1.z); us[7]=f2bf(f1.w);
  *(uint4*)(xb + i) = *(uint4*)&us[0];
}

// ---------- kernel 3: QKV GEMM, m97-style: 128x128 tile, BK=64, global_load_lds ----------
__global__ __launch_bounds__(256, 2) void qkv_gemm(const ushort* __restrict__ xb,
    const ushort* __restrict__ Wt, ushort* __restrict__ qo,
    ushort* __restrict__ ko, ushort* __restrict__ vTo) {
  const int m0 = blockIdx.x * 128;
  const int mat = blockIdx.y;
  const ushort* Bsrc = Wt + (size_t)mat * H_ * E_;
  __shared__ ushort As[2][128 * 64];
  __shared__ ushort Bs[2][128 * 64];
  const int tid = threadIdx.x;
  const int wave = tid >> 6, lane = tid & 63;
  const int col = lane & 15, quad = lane >> 4;
  const int wr = wave >> 1, wc = wave & 1;

  f32x4 acc[4][4];
  #pragma unroll
  for (int i = 0; i < 4; i++)
    #pragma unroll
    for (int j = 0; j < 4; j++) acc[i][j] = (f32x4){0.f,0.f,0.f,0.f};

  const int srow = lane >> 3;
  const int sunit = (lane & 7) ^ srow;
  const int gcol = sunit * 8;

  #define STAGE_QKV(it, bufi) do { \
    _Pragma("unroll") \
    for (int j = 0; j < 4; j++) { \
      int rbase = wave*8 + j*32; \
      GLLDS16(xb + (size_t)(m0 + rbase + srow) * E_ + (it)*64 + gcol, \
              &As[bufi][rbase * 64]); \
      GLLDS16(Bsrc + (size_t)(rbase + srow) * E_ + (it)*64 + gcol, \
              &Bs[bufi][rbase * 64]); \
    } \
  } while (0)

  STAGE_QKV(0, 0);
  __syncthreads();

  for (int it = 0; it < 16; it++) {
    if (it < 15) STAGE_QKV(it + 1, (it + 1) & 1);
    const ushort* a = &As[it & 1][0];
    const ushort* bb = &Bs[it & 1][0];
    #pragma unroll
    for (int kc = 0; kc < 2; kc++) {
      bf16x8 af[4], bf[4];
      #pragma unroll
      for (int mi = 0; mi < 4; mi++) {
        int rr = wr*64 + mi*16 + col;
        af[mi] = *(const bf16x8*)(a + rr*64 + (((kc*4 + quad) ^ (col & 7)) * 8));
      }
      #pragma unroll
      for (int ni = 0; ni < 4; ni++) {
        int rr = wc*64 + ni*16 + col;
        bf[ni] = *(const bf16x8*)(bb + rr*64 + (((kc*4 + quad) ^ (col & 7)) * 8));
      }
      #pragma unroll
      for (int mi = 0; mi < 4; mi++)
        #pragma unroll
        for (int ni = 0; ni < 4; ni++)
          acc[mi][ni] = __builtin_amdgcn_mfma_f32_16x16x32_bf16(af[mi], bf[ni], acc[mi][ni], 0, 0, 0);
    }
    __syncthreads();
  }

  if (mat == 2) {
    int bb = m0 >> 12;
    int sbase = (m0 & 4095) + wr * 64;
    #pragma unroll
    for (int ni = 0; ni < 4; ni++) {
      int n = wc*64 + ni*16 + col;
      #pragma unroll
      for (int mi = 0; mi < 4; mi++) {
        int s = sbase + mi*16 + quad*4;
        ushort4 o;
        o.x = f2bf(acc[mi][ni][0]); o.y = f2bf(acc[mi][ni][1]);
        o.z = f2bf(acc[mi][ni][2]); o.w = f2bf(acc[mi][ni][3]);
        *(ushort4*)(vTo + ((size_t)(bb * H_ + n)) * S_ + s) = o;
      }
    }
  } else {
    ushort* dst = (mat == 0 ? qo : ko);
    #pragma unroll
    for (int ni = 0; ni < 4; ni++) {
      int n = wc*64 + ni*16 + col;
      #pragma unroll
      for (int mi = 0; mi < 4; mi++) {
        int row = m0 + wr*64 + mi*16 + quad*4;
        #pragma unroll
        for (int r = 0; r < 4; r++)
          dst[(size_t)(row + r) * H_ + n] = f2bf(acc[mi][ni][r]);
      }
    }
  }
}

// ---------- kernel 4: causal flash, split-K, ONE 64-row tile per WG, KVBLK=32 ----------
// grid (c=8, t=64 reversed, b=4): 1152 active blocks.
// Body == R5 (reg-staged K, 16KB LDS, permlane softmax, in-reg P, T13/T14).
// REGISTER-ALLOCATOR HISTORY (the actual bottleneck, rounds 1-5):
//   pair body, (256,2):            est. pressure > 8-wave budget -> 112 VGPR, 84.8us
//   single body, (256,2) or (256,4): heuristic targets 8 waves/EU -> 64 VGPR, SPILLS, ~143us
// Fix: amdgpu_waves_per_eu(2,4) pins the scheduler's occupancy target at 4 waves/EU
// (128-reg budget) so the ~100-reg live set allocates without spill, while 4 blocks/CU
// capacity meets the 1152-block grid's 4.5 blocks/CU demand.
#define CHUNK_ 512
__global__ __launch_bounds__(256)
__attribute__((amdgpu_waves_per_eu(2, 4)))
void flash_kernel(const ushort* __restrict__ q,
    const ushort* __restrict__ k, const ushort* __restrict__ vT,
    float* __restrict__ Opart, float* __restrict__ ml) {
  const float SL2E = 0.08838834764831845f * 1.44269504088896340736f;
  int c = blockIdx.x;
  int t = 63 - (int)blockIdx.y;               // heavy tiles first
  int b = blockIdx.z;
  if (t < 8 * c) return;
  int a = t >> 3, rr = t & 7;
  int slot = b * 288 + (a + 1) * (4 * a + rr) + c;

  int wave = threadIdx.x >> 6, lane = threadIdx.x & 63;
  int col = lane & 15, quad = lane >> 4;
  int q0 = t * 64 + wave * 16;
  const ushort* qb = q + (size_t)b * S_ * H_;
  const ushort* kbp = k + (size_t)b * S_ * H_;
  const ushort* vb = vT + (size_t)b * H_ * S_;

  __shared__ ushort kl[2][32 * 128];          // K block double-buffer, 16 KB

  bf16x8 qf[4];
  {
    const ushort* qp = qb + (size_t)(q0 + col) * H_ + quad * 8;
    #pragma unroll
    for (int kc = 0; kc < 4; kc++) qf[kc] = *(const bf16x8*)(qp + kc * 32);
  }

  f32x4 O[8];
  #pragma unroll
  for (int d = 0; d < 8; d++) O[d] = (f32x4){0.f,0.f,0.f,0.f};
  float m = -1e30f, l = 0.f;

  const int c0 = c * CHUNK_;
  const int kend = min(c0 + CHUNK_, t * 64 + 64);
  const int nblk = (kend - c0 + 31) >> 5;
  const int qlim = q0 + 15;

  const int sk0 = wave * 8 + quad;            // staged K row (this thread), +4 for second
  const int gu0 = (col ^ (sk0 & 15)) * 8;     // pre-swizzled global src unit
  const int gu1 = (col ^ ((sk0 + 4) & 15)) * 8;
  ushort* ld0 = &kl[0][sk0 * 128 + col * 8];
  ushort* ld1 = &kl[0][(sk0 + 4) * 128 + col * 8];
  const size_t lbuf = 32 * 128;

  const ushort* vbase = vb + (size_t)col * S_ + c0 + quad * 8;

  { // prologue: stage block 0
    const ushort* kp = kbp + (size_t)(c0 + sk0) * H_;
    *(uint4*)ld0 = *(const uint4*)(kp + gu0);
    *(uint4*)ld1 = *(const uint4*)(kp + 4 * H_ + gu1);
  }
  __syncthreads();

  for (int ib = 0; ib < nblk; ib++) {
    const int kb0 = c0 + ib * 32;
    uint4 a0, a1;
    const bool pre = (ib + 1 < nblk);
    if (pre) {                                // T14: issue loads now, write LDS after compute
      const ushort* kp = kbp + (size_t)(kb0 + 32 + sk0) * H_;
      a0 = *(const uint4*)(kp + gu0);
      a1 = *(const uint4*)(kp + 4 * H_ + gu1);
    }
    if (kb0 <= qlim) {                        // wave-uniform
      // K fragments from LDS
      const ushort* kcur = &kl[ib & 1][0];
      bf16x8 kf0[4], kf1[4];
      #pragma unroll
      for (int kc = 0; kc < 4; kc++) {
        int u = quad + kc * 4;
        kf0[kc] = *(const bf16x8*)(kcur + col*128        + ((u ^ col) * 8));
        kf1[kc] = *(const bf16x8*)(kcur + (16 + col)*128 + ((u ^ col) * 8));
      }
      // QK^T: two independent chains
      f32x4 sv0 = (f32x4){0.f,0.f,0.f,0.f}, sv1 = (f32x4){0.f,0.f,0.f,0.f};
      __builtin_amdgcn_s_setprio(1);
      #pragma unroll
      for (int kc = 0; kc < 4; kc++) {
        sv0 = __builtin_amdgcn_mfma_f32_16x16x32_bf16(kf0[kc], qf[kc], sv0, 0, 0, 0);
        sv1 = __builtin_amdgcn_mfma_f32_16x16x32_bf16(kf1[kc], qf[kc], sv1, 0, 0, 0);
      }
      __builtin_amdgcn_s_setprio(0);
      // V fragments group 0 (d=0..3): issue before softmax
      bf16x8 vfA[4];
      #pragma unroll
      for (int j = 0; j < 4; j++)
        vfA[j] = *(const bf16x8*)(vbase + ib * 32 + (size_t)(j * 16) * S_);
      // softmax: s[r]=key kb0+quad*4+r, s[4+r]=key kb0+16+quad*4+r; row q0+col
      float s[8];
      #pragma unroll
      for (int r = 0; r < 4; r++) { s[r] = sv0[r]; s[4 + r] = sv1[r]; }
      if (kb0 + 31 > q0) {
        #pragma unroll
        for (int r = 0; r < 4; r++) {
          if (kb0 + quad * 4 + r      > q0 + col) s[r]     = -1e30f;
          if (kb0 + 16 + quad * 4 + r > q0 + col) s[4 + r] = -1e30f;
        }
      }
      float cm = s[0];
      #pragma unroll
      for (int j = 1; j < 8; j++) cm = fmaxf(cm, s[j]);
      cm = red4max(cm);
      if (!__all(cm <= m)) {                  // T13 exact skip (alpha==1 bit-identical)
        float mn = fmaxf(m, cm);
        float alpha = exp2f((m - mn) * SL2E);
        l *= alpha;
        #pragma unroll
        for (int d = 0; d < 8; d++) O[d] *= alpha;
        m = mn;
      }
      // V group 1 (d=4..7): issue mid-softmax
      bf16x8 vfB[4];
      #pragma unroll
      for (int j = 0; j < 4; j++)
        vfB[j] = *(const bf16x8*)(vbase + ib * 32 + (size_t)((4 + j) * 16) * S_);
      // p overwrites s in place (saves 8 regs vs separate p[])
      float rs = 0.f;
      #pragma unroll
      for (int j = 0; j < 8; j++) { s[j] = exp2f((s[j] - m) * SL2E); rs += s[j]; }
      l += red4sum(rs);
      // P -> bf16x8 B-fragment, in-register permlane network (all-static indexing)
      unsigned w0 = cvt_pk_bf16(s[0], s[1]);
      unsigned w1 = cvt_pk_bf16(s[2], s[3]);
      unsigned w2 = cvt_pk_bf16(s[4], s[5]);
      unsigned w3 = cvt_pk_bf16(s[6], s[7]);
      pl32sw(w0, w2); pl32sw(w1, w3);
      pl16sw(w0, w2); pl16sw(w1, w3);
      union { uint4 u4; bf16x8 v; } pu;
      pu.u4 = make_uint4(w0, w1, w2, w3);
      // PV
      __builtin_amdgcn_s_setprio(1);
      #pragma unroll
      for (int j = 0; j < 4; j++)
        O[j] = __builtin_amdgcn_mfma_f32_16x16x32_bf16(vfA[j], pu.v, O[j], 0, 0, 0);
      #pragma unroll
      for (int j = 0; j < 4; j++)
        O[4 + j] = __builtin_amdgcn_mfma_f32_16x16x32_bf16(vfB[j], pu.v, O[4 + j], 0, 0, 0);
      __builtin_amdgcn_s_setprio(0);
    }
    if (pre) {                                // LDS write late: vmcnt hidden under compute
      size_t off = ((ib + 1) & 1) * lbuf;
      *(uint4*)(ld0 + off) = a0;
      *(uint4*)(ld1 + off) = a1;
    }
    __syncthreads();
  }

  float* Op = Opart + (size_t)slot * (64 * 128) + (size_t)(wave * 16 + col) * 128 + quad * 4;
  #pragma unroll
  for (int d = 0; d < 8; d++) *(f32x4*)(Op + d * 16) = O[d];
  if (quad == 0)
    *(float2*)(ml + (size_t)slot * 128 + (size_t)(wave * 16 + col) * 2) = make_float2(m, l);
}

// ---------- kernel 5: combine split-K partials ----------
__global__ __launch_bounds__(256) void combine_kernel(const float* __restrict__ Opart,
    const float* __restrict__ ml, float* __restrict__ out) {
  const float SL2E = 0.08838834764831845f * 1.44269504088896340736f;
  int tile = blockIdx.x, b = blockIdx.y;
  int a = tile >> 3, rr = tile & 7;
  int nc = a + 1;
  int base = b * 288 + (a + 1) * (4 * a + rr);
  int tid = threadIdx.x;
  int row = tid >> 2;
  int cs = (tid & 3) * 4;
  float m_c[8], l_c[8];
  float mstar = -1e30f;
  for (int ci = 0; ci < nc; ci++) {
    m_c[ci] = ml[(size_t)(base + ci) * 128 + row * 2];
    l_c[ci] = ml[(size_t)(base + ci) * 128 + row * 2 + 1];
    mstar = fmaxf(mstar, m_c[ci]);
  }
  float denom = 0.f;
  float w_c[8];
  for (int ci = 0; ci < nc; ci++) {
    w_c[ci] = exp2f((m_c[ci] - mstar) * SL2E);
    denom += w_c[ci] * l_c[ci];
  }
  float inv = 1.f / denom;
  f32x4 acc[8];
  #pragma unroll
  for (int i = 0; i < 8; i++) acc[i] = (f32x4){0.f,0.f,0.f,0.f};
  for (int ci = 0; ci < nc; ci++) {
    const float* Op = Opart + (size_t)(base + ci) * (64 * 128) + row * 128;
    float w = w_c[ci];
    #pragma unroll
    for (int i = 0; i < 8; i++) {
      f32x4 v = *(const f32x4*)(Op + cs + i * 16);
      acc[i] += w * v;
    }
  }
  float* o = out + ((size_t)(b * S_) + tile * 64 + row) * H_;
  #pragma unroll
  for (int i = 0; i < 8; i++) {
    f32x4 v = acc[i] * inv;
    *(f32x4*)(o + cs + i * 16) = v;
  }
}

extern "C" void kernel_launch(void* const* d_in, const int* in_sizes, int n_in,
                              void* d_out, int out_size, void* d_ws, size_t ws_size,
                              hipStream_t stream) {
  (void)in_sizes; (void)n_in; (void)out_size; (void)ws_size;
  const float* x  = (const float*)d_in[0];
  const float* Wq = (const float*)d_in[1];
  const float* Wk = (const float*)d_in[2];
  const float* Wv = (const float*)d_in[3];
  float* out = (float*)d_out;
  char* ws = (char*)d_ws;
  ushort* Wt = (ushort*)ws;                                        // 768 KB
  ushort* qb = (ushort*)(ws + 786432);                             // 4 MB each
  ushort* kb = qb + (size_t)M_ * H_;
  ushort* vT = kb + (size_t)M_ * H_;
  float* Opart = (float*)(ws + 786432 + 3 * (size_t)M_ * H_ * 2);  // 36 MB
  float* ml = Opart + (size_t)1152 * 64 * 128;                     // 0.6 MB
  ushort* xbuf = (ushort*)Opart;   // alias: xb dead before flash writes Opart

  hipLaunchKernelGGL(wt_kernel,   dim3(384), dim3(256), 0, stream, Wq, Wk, Wv, Wt);
  hipLaunchKernelGGL(xb_kernel,   dim3(8192), dim3(256), 0, stream, x, xbuf);
  hipLaunchKernelGGL(qkv_gemm,    dim3(128, 3), dim3(256), 0, stream, xbuf, Wt, qb, kb, vT);
  hipLaunchKernelGGL(flash_kernel,dim3(8, 64, 4), dim3(256), 0, stream, qb, kb, vT, Opart, ml);
  hipLaunchKernelGGL(combine_kernel, dim3(64, 4), dim3(256), 0, stream, Opart, ml, out);
}

// Round 7
// 217.633 us; speedup vs baseline: 1.2569x; 1.2569x over previous
//
#include <hip/hip_runtime.h>

#define B_ 4
#define S_ 4096
#define E_ 1024
#define H_ 128
#define M_ (B_*S_)   // 16384

typedef __attribute__((ext_vector_type(8))) short bf16x8;
typedef __attribute__((ext_vector_type(4))) float f32x4;
typedef __attribute__((ext_vector_type(2))) unsigned int uint2v;

__device__ inline ushort f2bf(float f) {
  union { float f; unsigned u; } v; v.f = f;
  unsigned r = v.u + 0x7fffu + ((v.u >> 16) & 1u);   // RNE
  return (ushort)(r >> 16);
}

// ---- gfx950 cross-lane primitives (register-file, ~2cyc vs ~120cyc ds_bpermute) ----
__device__ inline void pl16sw(unsigned &x, unsigned &y) {
#if __has_builtin(__builtin_amdgcn_permlane16_swap)
  uint2v r = __builtin_amdgcn_permlane16_swap(x, y, false, false);
  x = r.x; y = r.y;
#else
  asm("v_permlane16_swap_b32 %0, %1" : "+v"(x), "+v"(y));
#endif
}
__device__ inline void pl32sw(unsigned &x, unsigned &y) {
#if __has_builtin(__builtin_amdgcn_permlane32_swap)
  uint2v r = __builtin_amdgcn_permlane32_swap(x, y, false, false);
  x = r.x; y = r.y;
#else
  asm("v_permlane32_swap_b32 %0, %1" : "+v"(x), "+v"(y));
#endif
}
// reduce over the 4 quads (lanes {col, col+16, col+32, col+48}); result broadcast to all
__device__ inline float red4max(float v) {
  union { float f; unsigned u; } a, b;
  a.f = v; b.f = v; pl16sw(a.u, b.u);
  float m1 = fmaxf(a.f, b.f);
  a.f = m1; b.f = m1; pl32sw(a.u, b.u);
  return fmaxf(a.f, b.f);
}
__device__ inline float red4sum(float v) {
  union { float f; unsigned u; } a, b;
  a.f = v; b.f = v; pl16sw(a.u, b.u);
  float s1 = a.f + b.f;
  a.f = s1; b.f = s1; pl32sw(a.u, b.u);
  return a.f + b.f;
}
__device__ inline unsigned cvt_pk_bf16(float lo, float hi) {
  unsigned w;
  asm("v_cvt_pk_bf16_f32 %0, %1, %2" : "=v"(w) : "v"(lo), "v"(hi));
  return w;
}

#define GLLDS16(g, l) __builtin_amdgcn_global_load_lds( \
    (const __attribute__((address_space(1))) void*)(g), \
    (__attribute__((address_space(3))) void*)(l), 16, 0, 0)

// ---------- kernel 1: W [1024][128] f32 (x3) -> Wt [3][128][1024] bf16 ----------
__global__ __launch_bounds__(256) void wt_kernel(const float* __restrict__ Wq,
    const float* __restrict__ Wk, const float* __restrict__ Wv,
    ushort* __restrict__ Wt) {
  int bid = blockIdx.x;               // 384 = 3 mats * 4 h-tiles * 32 e-tiles
  int mat = bid >> 7;
  int rem = bid & 127;
  int ht = rem >> 5, et = rem & 31;
  const float* W = mat == 0 ? Wq : (mat == 1 ? Wk : Wv);
  int e0 = et * 32, h0 = ht * 32;
  __shared__ float tl[32][33];
  int t = threadIdx.x;
  int r = t >> 3, c = (t & 7) << 2;
  const float4 f = *(const float4*)(W + (size_t)(e0 + r) * H_ + h0 + c);
  tl[r][c] = f.x; tl[r][c+1] = f.y; tl[r][c+2] = f.z; tl[r][c+3] = f.w;
  __syncthreads();
  ushort4 o;
  o.x = f2bf(tl[c+0][r]); o.y = f2bf(tl[c+1][r]);
  o.z = f2bf(tl[c+2][r]); o.w = f2bf(tl[c+3][r]);
  *(ushort4*)(Wt + ((size_t)mat*H_ + h0 + r) * E_ + e0 + c) = o;
}

// ---------- kernel 2: x f32 -> bf16 (memory-bound) ----------
__global__ __launch_bounds__(256) void xb_kernel(const float* __restrict__ x,
                                                 ushort* __restrict__ xb) {
  size_t i = ((size_t)blockIdx.x * 256 + threadIdx.x) * 8;
  float4 f0 = *(const float4*)(x + i);
  float4 f1 = *(const float4*)(x + i + 4);
  alignas(16) ushort us[8];
  us[0]=f2bf(f0.x); us[1]=f2bf(f0.y); us[2]=f2bf(f0.z); us[3]=f2bf(f0.w);
  us[4]=f2bf(f1.x); us[5]=f2bf(f1.y); us[6]=f2bf(f1.z); us[7]=f2bf(f1.w);
  *(uint4*)(xb + i) = *(uint4*)&us[0];
}

// ---------- kernel 3: QKV GEMM, m97-style: 128x128 tile, BK=64, global_load_lds ----------
__global__ __launch_bounds__(256, 2) void qkv_gemm(const ushort* __restrict__ xb,
    const ushort* __restrict__ Wt, ushort* __restrict__ qo,
    ushort* __restrict__ ko, ushort* __restrict__ vTo) {
  const int m0 = blockIdx.x * 128;
  const int mat = blockIdx.y;
  const ushort* Bsrc = Wt + (size_t)mat * H_ * E_;
  __shared__ ushort As[2][128 * 64];
  __shared__ ushort Bs[2][128 * 64];
  const int tid = threadIdx.x;
  const int wave = tid >> 6, lane = tid & 63;
  const int col = lane & 15, quad = lane >> 4;
  const int wr = wave >> 1, wc = wave & 1;

  f32x4 acc[4][4];
  #pragma unroll
  for (int i = 0; i < 4; i++)
    #pragma unroll
    for (int j = 0; j < 4; j++) acc[i][j] = (f32x4){0.f,0.f,0.f,0.f};

  const int srow = lane >> 3;
  const int sunit = (lane & 7) ^ srow;
  const int gcol = sunit * 8;

  #define STAGE_QKV(it, bufi) do { \
    _Pragma("unroll") \
    for (int j = 0; j < 4; j++) { \
      int rbase = wave*8 + j*32; \
      GLLDS16(xb + (size_t)(m0 + rbase + srow) * E_ + (it)*64 + gcol, \
              &As[bufi][rbase * 64]); \
      GLLDS16(Bsrc + (size_t)(rbase + srow) * E_ + (it)*64 + gcol, \
              &Bs[bufi][rbase * 64]); \
    } \
  } while (0)

  STAGE_QKV(0, 0);
  __syncthreads();

  for (int it = 0; it < 16; it++) {
    if (it < 15) STAGE_QKV(it + 1, (it + 1) & 1);
    const ushort* a = &As[it & 1][0];
    const ushort* bb = &Bs[it & 1][0];
    #pragma unroll
    for (int kc = 0; kc < 2; kc++) {
      bf16x8 af[4], bf[4];
      #pragma unroll
      for (int mi = 0; mi < 4; mi++) {
        int rr = wr*64 + mi*16 + col;
        af[mi] = *(const bf16x8*)(a + rr*64 + (((kc*4 + quad) ^ (col & 7)) * 8));
      }
      #pragma unroll
      for (int ni = 0; ni < 4; ni++) {
        int rr = wc*64 + ni*16 + col;
        bf[ni] = *(const bf16x8*)(bb + rr*64 + (((kc*4 + quad) ^ (col & 7)) * 8));
      }
      #pragma unroll
      for (int mi = 0; mi < 4; mi++)
        #pragma unroll
        for (int ni = 0; ni < 4; ni++)
          acc[mi][ni] = __builtin_amdgcn_mfma_f32_16x16x32_bf16(af[mi], bf[ni], acc[mi][ni], 0, 0, 0);
    }
    __syncthreads();
  }

  if (mat == 2) {
    int bb = m0 >> 12;
    int sbase = (m0 & 4095) + wr * 64;
    #pragma unroll
    for (int ni = 0; ni < 4; ni++) {
      int n = wc*64 + ni*16 + col;
      #pragma unroll
      for (int mi = 0; mi < 4; mi++) {
        int s = sbase + mi*16 + quad*4;
        ushort4 o;
        o.x = f2bf(acc[mi][ni][0]); o.y = f2bf(acc[mi][ni][1]);
        o.z = f2bf(acc[mi][ni][2]); o.w = f2bf(acc[mi][ni][3]);
        *(ushort4*)(vTo + ((size_t)(bb * H_ + n)) * S_ + s) = o;
      }
    }
  } else {
    ushort* dst = (mat == 0 ? qo : ko);
    #pragma unroll
    for (int ni = 0; ni < 4; ni++) {
      int n = wc*64 + ni*16 + col;
      #pragma unroll
      for (int mi = 0; mi < 4; mi++) {
        int row = m0 + wr*64 + mi*16 + quad*4;
        #pragma unroll
        for (int r = 0; r < 4; r++)
          dst[(size_t)(row + r) * H_ + n] = f2bf(acc[mi][ni][r]);
      }
    }
  }
}

// ---------- kernel 4: causal flash, tile-PAIR per WG + 2-deep QK pipeline ----------
// Back to the PAIR body (the only shape the backend allocates fat: 112 VGPR, 84.8us;
// single-tile bodies get serialized to 64 VGPR regardless of bounds/attrs - R1/R5/R6).
// New: triple-buffered K LDS (24KB) + QK(i+1) computed right after the barrier, fully
// independent of softmax(i)+PV(i) -> kf ds_reads + 16 QK MFMAs leave the serial chain.
// Race proof (1 barrier/iter): write(i+1)->buf[(i+1)%3]; nearest prior reader of that
// buffer is QK(i-2), separated by barriers i-1 and i. T14 K-reg loads 2 blocks ahead.
#define CHUNK_ 512
__global__ __launch_bounds__(256, 2) void flash_kernel(const ushort* __restrict__ q,
    const ushort* __restrict__ k, const ushort* __restrict__ vT,
    float* __restrict__ Opart, float* __restrict__ ml) {
  const float SL2E = 0.08838834764831845f * 1.44269504088896340736f;
  int c = blockIdx.x;
  int tp = 31 - (int)blockIdx.y;              // heavy pairs first
  int b = blockIdx.z;
  if (tp < 4 * c) return;
  int tA = tp * 2, tB = tA + 1;
  int aA = tA >> 3, rA = tA & 7;
  int aB = tB >> 3, rB = tB & 7;
  int slotA = b * 288 + (aA + 1) * (4 * aA + rA) + c;
  int slotB = b * 288 + (aB + 1) * (4 * aB + rB) + c;

  int wave = threadIdx.x >> 6, lane = threadIdx.x & 63;
  int col = lane & 15, quad = lane >> 4;
  int q0A = tA * 64 + wave * 16;
  int q0B = q0A + 64;
  const ushort* qb = q + (size_t)b * S_ * H_;
  const ushort* kbp = k + (size_t)b * S_ * H_;
  const ushort* vb = vT + (size_t)b * H_ * S_;

  __shared__ ushort kl[3][32 * 128];          // TRIPLE buffer, XOR-swizzled 16B units

  bf16x8 qfA[4], qfB[4];
  {
    const ushort* qpA = qb + (size_t)(q0A + col) * H_ + quad * 8;
    const ushort* qpB = qb + (size_t)(q0B + col) * H_ + quad * 8;
    #pragma unroll
    for (int kc = 0; kc < 4; kc++) {
      qfA[kc] = *(const bf16x8*)(qpA + kc * 32);
      qfB[kc] = *(const bf16x8*)(qpB + kc * 32);
    }
  }

  f32x4 OA[8], OB[8];
  #pragma unroll
  for (int d = 0; d < 8; d++) { OA[d] = (f32x4){0.f,0.f,0.f,0.f}; OB[d] = (f32x4){0.f,0.f,0.f,0.f}; }
  float mA = -1e30f, lA = 0.f, mB = -1e30f, lB = 0.f;

  const int c0 = c * CHUNK_;
  const int kendWG = min(c0 + CHUNK_, tB * 64 + 64);
  const int nblk = (kendWG - c0 + 31) >> 5;   // >= 4 for active blocks
  const int qlimA = q0A + 15, qlimB = q0B + 15;

  const int sk0 = wave * 8 + quad;            // staged K rows sk0 and sk0+4
  const int gu0 = (col ^ (sk0 & 15)) * 8;     // pre-swizzled global src unit
  const int gu1 = (col ^ ((sk0 + 4) & 15)) * 8;
  const int lo0 = sk0 * 128 + col * 8;        // LDS offsets within a buffer
  const int lo1 = (sk0 + 4) * 128 + col * 8;

  const ushort* vbase = vb + (size_t)col * S_ + c0 + quad * 8;

  uint4 a0, a1;
  { // prologue: stage block 0 directly to buf 0
    const ushort* kp = kbp + (size_t)(c0 + sk0) * H_;
    a0 = *(const uint4*)(kp + gu0);
    a1 = *(const uint4*)(kp + 4 * H_ + gu1);
    *(uint4*)(&kl[0][lo0]) = a0;
    *(uint4*)(&kl[0][lo1]) = a1;
  }
  if (nblk > 1) { // preload block 1 into regs
    const ushort* kp = kbp + (size_t)(c0 + 32 + sk0) * H_;
    a0 = *(const uint4*)(kp + gu0);
    a1 = *(const uint4*)(kp + 4 * H_ + gu1);
  }
  __syncthreads();

  // QK(0) -> current score state (kb=c0 <= qlimA always for active waves)
  f32x4 cB0, cB1, cA0, cA1;
  {
    const ushort* kcur = &kl[0][0];
    bf16x8 kf0[4], kf1[4];
    #pragma unroll
    for (int kc = 0; kc < 4; kc++) {
      int u = quad + kc * 4;
      kf0[kc] = *(const bf16x8*)(kcur + col*128        + ((u ^ col) * 8));
      kf1[kc] = *(const bf16x8*)(kcur + (16 + col)*128 + ((u ^ col) * 8));
    }
    cB0 = (f32x4){0.f,0.f,0.f,0.f}; cB1 = cB0; cA0 = cB0; cA1 = cB0;
    __builtin_amdgcn_s_setprio(1);
    #pragma unroll
    for (int kc = 0; kc < 4; kc++) {
      cB0 = __builtin_amdgcn_mfma_f32_16x16x32_bf16(kf0[kc], qfB[kc], cB0, 0, 0, 0);
      cB1 = __builtin_amdgcn_mfma_f32_16x16x32_bf16(kf1[kc], qfB[kc], cB1, 0, 0, 0);
      cA0 = __builtin_amdgcn_mfma_f32_16x16x32_bf16(kf0[kc], qfA[kc], cA0, 0, 0, 0);
      cA1 = __builtin_amdgcn_mfma_f32_16x16x32_bf16(kf1[kc], qfA[kc], cA1, 0, 0, 0);
    }
    __builtin_amdgcn_s_setprio(0);
  }

  int bw = 1;                                 // LDS buffer that receives K(ib+1)
  for (int ib = 0; ib < nblk; ib++) {
    const int kb0 = c0 + ib * 32;
    const int kb1 = kb0 + 32;
    if (ib + 1 < nblk) {                      // write K(ib+1) regs -> LDS buf bw
      *(uint4*)(&kl[bw][lo0]) = a0;
      *(uint4*)(&kl[bw][lo1]) = a1;
    }
    __syncthreads();
    if (ib + 2 < nblk) {                      // T14: load K(ib+2) regs
      const ushort* kp = kbp + (size_t)(kb0 + 64 + sk0) * H_;
      a0 = *(const uint4*)(kp + gu0);
      a1 = *(const uint4*)(kp + 4 * H_ + gu1);
    }
    // ---- QK(ib+1) -> next state (independent of softmax(ib)/PV(ib) below) ----
    f32x4 nB0 = (f32x4){0.f,0.f,0.f,0.f}, nB1 = nB0, nA0 = nB0, nA1 = nB0;
    if (ib + 1 < nblk && kb1 <= qlimB) {
      const ushort* kcur = &kl[bw][0];
      bf16x8 kf0[4], kf1[4];
      #pragma unroll
      for (int kc = 0; kc < 4; kc++) {
        int u = quad + kc * 4;
        kf0[kc] = *(const bf16x8*)(kcur + col*128        + ((u ^ col) * 8));
        kf1[kc] = *(const bf16x8*)(kcur + (16 + col)*128 + ((u ^ col) * 8));
      }
      __builtin_amdgcn_s_setprio(1);
      #pragma unroll
      for (int kc = 0; kc < 4; kc++) {
        nB0 = __builtin_amdgcn_mfma_f32_16x16x32_bf16(kf0[kc], qfB[kc], nB0, 0, 0, 0);
        nB1 = __builtin_amdgcn_mfma_f32_16x16x32_bf16(kf1[kc], qfB[kc], nB1, 0, 0, 0);
      }
      if (kb1 <= qlimA) {
        #pragma unroll
        for (int kc = 0; kc < 4; kc++) {
          nA0 = __builtin_amdgcn_mfma_f32_16x16x32_bf16(kf0[kc], qfA[kc], nA0, 0, 0, 0);
          nA1 = __builtin_amdgcn_mfma_f32_16x16x32_bf16(kf1[kc], qfA[kc], nA1, 0, 0, 0);
        }
      }
      __builtin_amdgcn_s_setprio(0);
    }
    // ---- iter ib: softmax + PV from current score state ----
    if (kb0 <= qlimB) {                       // wave-uniform
      const bool doA = (kb0 <= qlimA);
      bf16x8 vf03[4];
      #pragma unroll
      for (int j = 0; j < 4; j++)
        vf03[j] = *(const bf16x8*)(vbase + ib * 32 + (size_t)(j * 16) * S_);
      // ---- tile B softmax ----
      uint4 pfB4;
      {
        float s[8];
        #pragma unroll
        for (int r = 0; r < 4; r++) { s[r] = cB0[r]; s[4+r] = cB1[r]; }
        if (kb0 + 31 > q0B) {
          #pragma unroll
          for (int r = 0; r < 4; r++) {
            if (kb0 + quad*4 + r      > q0B + col) s[r]   = -1e30f;
            if (kb0 + 16 + quad*4 + r > q0B + col) s[4+r] = -1e30f;
          }
        }
        float cm = s[0];
        #pragma unroll
        for (int j = 1; j < 8; j++) cm = fmaxf(cm, s[j]);
        cm = red4max(cm);
        if (!__all(cm <= mB)) {               // T13 exact skip
          float mn = fmaxf(mB, cm);
          float alpha = exp2f((mB - mn) * SL2E);
          lB *= alpha;
          #pragma unroll
          for (int d = 0; d < 8; d++) OB[d] *= alpha;
          mB = mn;
        }
        float rs = 0.f;
        #pragma unroll
        for (int j = 0; j < 8; j++) { s[j] = exp2f((s[j] - mB) * SL2E); rs += s[j]; }
        lB += red4sum(rs);
        unsigned w0 = cvt_pk_bf16(s[0], s[1]);
        unsigned w1 = cvt_pk_bf16(s[2], s[3]);
        unsigned w2 = cvt_pk_bf16(s[4], s[5]);
        unsigned w3 = cvt_pk_bf16(s[6], s[7]);
        pl32sw(w0, w2); pl32sw(w1, w3);
        pl16sw(w0, w2); pl16sw(w1, w3);
        pfB4 = make_uint4(w0, w1, w2, w3);
      }
      bf16x8 vf47[4];                         // issue while softmaxA runs
      #pragma unroll
      for (int j = 0; j < 4; j++)
        vf47[j] = *(const bf16x8*)(vbase + ib * 32 + (size_t)((4 + j) * 16) * S_);
      // ---- tile A softmax ----
      uint4 pfA4 = make_uint4(0u, 0u, 0u, 0u);
      if (doA) {
        float s[8];
        #pragma unroll
        for (int r = 0; r < 4; r++) { s[r] = cA0[r]; s[4+r] = cA1[r]; }
        if (kb0 + 31 > q0A) {
          #pragma unroll
          for (int r = 0; r < 4; r++) {
            if (kb0 + quad*4 + r      > q0A + col) s[r]   = -1e30f;
            if (kb0 + 16 + quad*4 + r > q0A + col) s[4+r] = -1e30f;
          }
        }
        float cm = s[0];
        #pragma unroll
        for (int j = 1; j < 8; j++) cm = fmaxf(cm, s[j]);
        cm = red4max(cm);
        if (!__all(cm <= mA)) {
          float mn = fmaxf(mA, cm);
          float alpha = exp2f((mA - mn) * SL2E);
          lA *= alpha;
          #pragma unroll
          for (int d = 0; d < 8; d++) OA[d] *= alpha;
          mA = mn;
        }
        float rs = 0.f;
        #pragma unroll
        for (int j = 0; j < 8; j++) { s[j] = exp2f((s[j] - mA) * SL2E); rs += s[j]; }
        lA += red4sum(rs);
        unsigned w0 = cvt_pk_bf16(s[0], s[1]);
        unsigned w1 = cvt_pk_bf16(s[2], s[3]);
        unsigned w2 = cvt_pk_bf16(s[4], s[5]);
        unsigned w3 = cvt_pk_bf16(s[6], s[7]);
        pl32sw(w0, w2); pl32sw(w1, w3);
        pl16sw(w0, w2); pl16sw(w1, w3);
        pfA4 = make_uint4(w0, w1, w2, w3);
      }
      // ---- PV for both tiles (shared vf) ----
      {
        union { uint4 u4; bf16x8 v; } puB, puA;
        puB.u4 = pfB4; puA.u4 = pfA4;
        __builtin_amdgcn_s_setprio(1);
        #pragma unroll
        for (int j = 0; j < 4; j++)
          OB[j] = __builtin_amdgcn_mfma_f32_16x16x32_bf16(vf03[j], puB.v, OB[j], 0, 0, 0);
        if (doA) {
          #pragma unroll
          for (int j = 0; j < 4; j++)
            OA[j] = __builtin_amdgcn_mfma_f32_16x16x32_bf16(vf03[j], puA.v, OA[j], 0, 0, 0);
        }
        #pragma unroll
        for (int j = 0; j < 4; j++)
          OB[4 + j] = __builtin_amdgcn_mfma_f32_16x16x32_bf16(vf47[j], puB.v, OB[4 + j], 0, 0, 0);
        if (doA) {
          #pragma unroll
          for (int j = 0; j < 4; j++)
            OA[4 + j] = __builtin_amdgcn_mfma_f32_16x16x32_bf16(vf47[j], puA.v, OA[4 + j], 0, 0, 0);
        }
        __builtin_amdgcn_s_setprio(0);
      }
    }
    // rotate pipeline state (static names, no dynamic indexing)
    cB0 = nB0; cB1 = nB1; cA0 = nA0; cA1 = nA1;
    bw++; if (bw == 3) bw = 0;
  }

  float* OpA = Opart + (size_t)slotA * (64 * 128) + (size_t)(wave*16 + col) * 128 + quad * 4;
  float* OpB = Opart + (size_t)slotB * (64 * 128) + (size_t)(wave*16 + col) * 128 + quad * 4;
  #pragma unroll
  for (int d = 0; d < 8; d++) {
    *(f32x4*)(OpA + d * 16) = OA[d];
    *(f32x4*)(OpB + d * 16) = OB[d];
  }
  if (quad == 0) {
    *(float2*)(ml + (size_t)slotA * 128 + (size_t)(wave*16 + col) * 2) = make_float2(mA, lA);
    *(float2*)(ml + (size_t)slotB * 128 + (size_t)(wave*16 + col) * 2) = make_float2(mB, lB);
  }
}

// ---------- kernel 5: combine split-K partials ----------
__global__ __launch_bounds__(256) void combine_kernel(const float* __restrict__ Opart,
    const float* __restrict__ ml, float* __restrict__ out) {
  const float SL2E = 0.08838834764831845f * 1.44269504088896340736f;
  int tile = blockIdx.x, b = blockIdx.y;
  int a = tile >> 3, rr = tile & 7;
  int nc = a + 1;
  int base = b * 288 + (a + 1) * (4 * a + rr);
  int tid = threadIdx.x;
  int row = tid >> 2;
  int cs = (tid & 3) * 4;
  float m_c[8], l_c[8];
  float mstar = -1e30f;
  for (int ci = 0; ci < nc; ci++) {
    m_c[ci] = ml[(size_t)(base + ci) * 128 + row * 2];
    l_c[ci] = ml[(size_t)(base + ci) * 128 + row * 2 + 1];
    mstar = fmaxf(mstar, m_c[ci]);
  }
  float denom = 0.f;
  float w_c[8];
  for (int ci = 0; ci < nc; ci++) {
    w_c[ci] = exp2f((m_c[ci] - mstar) * SL2E);
    denom += w_c[ci] * l_c[ci];
  }
  float inv = 1.f / denom;
  f32x4 acc[8];
  #pragma unroll
  for (int i = 0; i < 8; i++) acc[i] = (f32x4){0.f,0.f,0.f,0.f};
  for (int ci = 0; ci < nc; ci++) {
    const float* Op = Opart + (size_t)(base + ci) * (64 * 128) + row * 128;
    float w = w_c[ci];
    #pragma unroll
    for (int i = 0; i < 8; i++) {
      f32x4 v = *(const f32x4*)(Op + cs + i * 16);
      acc[i] += w * v;
    }
  }
  float* o = out + ((size_t)(b * S_) + tile * 64 + row) * H_;
  #pragma unroll
  for (int i = 0; i < 8; i++) {
    f32x4 v = acc[i] * inv;
    *(f32x4*)(o + cs + i * 16) = v;
  }
}

extern "C" void kernel_launch(void* const* d_in, const int* in_sizes, int n_in,
                              void* d_out, int out_size, void* d_ws, size_t ws_size,
                              hipStream_t stream) {
  (void)in_sizes; (void)n_in; (void)out_size; (void)ws_size;
  const float* x  = (const float*)d_in[0];
  const float* Wq = (const float*)d_in[1];
  const float* Wk = (const float*)d_in[2];
  const float* Wv = (const float*)d_in[3];
  float* out = (float*)d_out;
  char* ws = (char*)d_ws;
  ushort* Wt = (ushort*)ws;                                        // 768 KB
  ushort* qb = (ushort*)(ws + 786432);                             // 4 MB each
  ushort* kb = qb + (size_t)M_ * H_;
  ushort* vT = kb + (size_t)M_ * H_;
  float* Opart = (float*)(ws + 786432 + 3 * (size_t)M_ * H_ * 2);  // 36 MB
  float* ml = Opart + (size_t)1152 * 64 * 128;                     // 0.6 MB
  ushort* xbuf = (ushort*)Opart;   // alias: xb dead before flash writes Opart

  hipLaunchKernelGGL(wt_kernel,   dim3(384), dim3(256), 0, stream, Wq, Wk, Wv, Wt);
  hipLaunchKernelGGL(xb_kernel,   dim3(8192), dim3(256), 0, stream, x, xbuf);
  hipLaunchKernelGGL(qkv_gemm,    dim3(128, 3), dim3(256), 0, stream, xbuf, Wt, qb, kb, vT);
  hipLaunchKernelGGL(flash_kernel,dim3(8, 32, 4), dim3(256), 0, stream, qb, kb, vT, Opart, ml);
  hipLaunchKernelGGL(combine_kernel, dim3(64, 4), dim3(256), 0, stream, Opart, ml, out);
}

// Round 8
// 208.655 us; speedup vs baseline: 1.3110x; 1.0430x over previous
//
#include <hip/hip_runtime.h>

#define B_ 4
#define S_ 4096
#define E_ 1024
#define H_ 128
#define M_ (B_*S_)   // 16384

typedef __attribute__((ext_vector_type(8))) short bf16x8;
typedef __attribute__((ext_vector_type(4))) float f32x4;
typedef __attribute__((ext_vector_type(2))) unsigned int uint2v;

__device__ inline ushort f2bf(float f) {
  union { float f; unsigned u; } v; v.f = f;
  unsigned r = v.u + 0x7fffu + ((v.u >> 16) & 1u);   // RNE
  return (ushort)(r >> 16);
}

// ---- gfx950 cross-lane primitives (register-file, ~2cyc vs ~120cyc ds_bpermute) ----
__device__ inline void pl16sw(unsigned &x, unsigned &y) {
#if __has_builtin(__builtin_amdgcn_permlane16_swap)
  uint2v r = __builtin_amdgcn_permlane16_swap(x, y, false, false);
  x = r.x; y = r.y;
#else
  asm("v_permlane16_swap_b32 %0, %1" : "+v"(x), "+v"(y));
#endif
}
__device__ inline void pl32sw(unsigned &x, unsigned &y) {
#if __has_builtin(__builtin_amdgcn_permlane32_swap)
  uint2v r = __builtin_amdgcn_permlane32_swap(x, y, false, false);
  x = r.x; y = r.y;
#else
  asm("v_permlane32_swap_b32 %0, %1" : "+v"(x), "+v"(y));
#endif
}
// reduce over the 4 quads (lanes {col, col+16, col+32, col+48}); result broadcast to all
__device__ inline float red4max(float v) {
  union { float f; unsigned u; } a, b;
  a.f = v; b.f = v; pl16sw(a.u, b.u);
  float m1 = fmaxf(a.f, b.f);
  a.f = m1; b.f = m1; pl32sw(a.u, b.u);
  return fmaxf(a.f, b.f);
}
__device__ inline float red4sum(float v) {
  union { float f; unsigned u; } a, b;
  a.f = v; b.f = v; pl16sw(a.u, b.u);
  float s1 = a.f + b.f;
  a.f = s1; b.f = s1; pl32sw(a.u, b.u);
  return a.f + b.f;
}
__device__ inline unsigned cvt_pk_bf16(float lo, float hi) {
  unsigned w;
  asm("v_cvt_pk_bf16_f32 %0, %1, %2" : "=v"(w) : "v"(lo), "v"(hi));
  return w;
}

#define GLLDS16(g, l) __builtin_amdgcn_global_load_lds( \
    (const __attribute__((address_space(1))) void*)(g), \
    (__attribute__((address_space(3))) void*)(l), 16, 0, 0)

// ---------- kernel 1: W [1024][128] f32 (x3) -> Wt [3][128][1024] bf16 ----------
__global__ __launch_bounds__(256) void wt_kernel(const float* __restrict__ Wq,
    const float* __restrict__ Wk, const float* __restrict__ Wv,
    ushort* __restrict__ Wt) {
  int bid = blockIdx.x;               // 384 = 3 mats * 4 h-tiles * 32 e-tiles
  int mat = bid >> 7;
  int rem = bid & 127;
  int ht = rem >> 5, et = rem & 31;
  const float* W = mat == 0 ? Wq : (mat == 1 ? Wk : Wv);
  int e0 = et * 32, h0 = ht * 32;
  __shared__ float tl[32][33];
  int t = threadIdx.x;
  int r = t >> 3, c = (t & 7) << 2;
  const float4 f = *(const float4*)(W + (size_t)(e0 + r) * H_ + h0 + c);
  tl[r][c] = f.x; tl[r][c+1] = f.y; tl[r][c+2] = f.z; tl[r][c+3] = f.w;
  __syncthreads();
  ushort4 o;
  o.x = f2bf(tl[c+0][r]); o.y = f2bf(tl[c+1][r]);
  o.z = f2bf(tl[c+2][r]); o.w = f2bf(tl[c+3][r]);
  *(ushort4*)(Wt + ((size_t)mat*H_ + h0 + r) * E_ + e0 + c) = o;
}

// ---------- kernel 2: x f32 -> bf16 (memory-bound) ----------
__global__ __launch_bounds__(256) void xb_kernel(const float* __restrict__ x,
                                                 ushort* __restrict__ xb) {
  size_t i = ((size_t)blockIdx.x * 256 + threadIdx.x) * 8;
  float4 f0 = *(const float4*)(x + i);
  float4 f1 = *(const float4*)(x + i + 4);
  alignas(16) ushort us[8];
  us[0]=f2bf(f0.x); us[1]=f2bf(f0.y); us[2]=f2bf(f0.z); us[3]=f2bf(f0.w);
  us[4]=f2bf(f1.x); us[5]=f2bf(f1.y); us[6]=f2bf(f1.z); us[7]=f2bf(f1.w);
  *(uint4*)(xb + i) = *(uint4*)&us[0];
}

// ---------- kernel 3: QKV GEMM, m97-style: 128x128 tile, BK=64, global_load_lds ----------
// mat==2 (V) epilogue now writes the TILED layout vT[b][g=key/32][dim 0..127][key&31]
// so flash's per-iteration V-tile is one contiguous 8KB block (see flash comment).
__global__ __launch_bounds__(256, 2) void qkv_gemm(const ushort* __restrict__ xb,
    const ushort* __restrict__ Wt, ushort* __restrict__ qo,
    ushort* __restrict__ ko, ushort* __restrict__ vTo) {
  const int m0 = blockIdx.x * 128;
  const int mat = blockIdx.y;
  const ushort* Bsrc = Wt + (size_t)mat * H_ * E_;
  __shared__ ushort As[2][128 * 64];
  __shared__ ushort Bs[2][128 * 64];
  const int tid = threadIdx.x;
  const int wave = tid >> 6, lane = tid & 63;
  const int col = lane & 15, quad = lane >> 4;
  const int wr = wave >> 1, wc = wave & 1;

  f32x4 acc[4][4];
  #pragma unroll
  for (int i = 0; i < 4; i++)
    #pragma unroll
    for (int j = 0; j < 4; j++) acc[i][j] = (f32x4){0.f,0.f,0.f,0.f};

  const int srow = lane >> 3;
  const int sunit = (lane & 7) ^ srow;
  const int gcol = sunit * 8;

  #define STAGE_QKV(it, bufi) do { \
    _Pragma("unroll") \
    for (int j = 0; j < 4; j++) { \
      int rbase = wave*8 + j*32; \
      GLLDS16(xb + (size_t)(m0 + rbase + srow) * E_ + (it)*64 + gcol, \
              &As[bufi][rbase * 64]); \
      GLLDS16(Bsrc + (size_t)(rbase + srow) * E_ + (it)*64 + gcol, \
              &Bs[bufi][rbase * 64]); \
    } \
  } while (0)

  STAGE_QKV(0, 0);
  __syncthreads();

  for (int it = 0; it < 16; it++) {
    if (it < 15) STAGE_QKV(it + 1, (it + 1) & 1);
    const ushort* a = &As[it & 1][0];
    const ushort* bb = &Bs[it & 1][0];
    #pragma unroll
    for (int kc = 0; kc < 2; kc++) {
      bf16x8 af[4], bf[4];
      #pragma unroll
      for (int mi = 0; mi < 4; mi++) {
        int rr = wr*64 + mi*16 + col;
        af[mi] = *(const bf16x8*)(a + rr*64 + (((kc*4 + quad) ^ (col & 7)) * 8));
      }
      #pragma unroll
      for (int ni = 0; ni < 4; ni++) {
        int rr = wc*64 + ni*16 + col;
        bf[ni] = *(const bf16x8*)(bb + rr*64 + (((kc*4 + quad) ^ (col & 7)) * 8));
      }
      #pragma unroll
      for (int mi = 0; mi < 4; mi++)
        #pragma unroll
        for (int ni = 0; ni < 4; ni++)
          acc[mi][ni] = __builtin_amdgcn_mfma_f32_16x16x32_bf16(af[mi], bf[ni], acc[mi][ni], 0, 0, 0);
    }
    __syncthreads();
  }

  if (mat == 2) {
    // TILED V write: vT[b][g][h][ks], g = key>>5, ks = key&31, h = dim.
    // The 4 keys s..s+3 share g (s%32 <= 28). Writes confined to 8KB tiles.
    int bb = m0 >> 12;
    int sbase = (m0 & 4095) + wr * 64;
    #pragma unroll
    for (int ni = 0; ni < 4; ni++) {
      int n = wc*64 + ni*16 + col;
      #pragma unroll
      for (int mi = 0; mi < 4; mi++) {
        int s = sbase + mi*16 + quad*4;
        ushort4 o;
        o.x = f2bf(acc[mi][ni][0]); o.y = f2bf(acc[mi][ni][1]);
        o.z = f2bf(acc[mi][ni][2]); o.w = f2bf(acc[mi][ni][3]);
        *(ushort4*)(vTo + ((size_t)(bb * 128 + (s >> 5)) * 128 + n) * 32 + (s & 31)) = o;
      }
    }
  } else {
    ushort* dst = (mat == 0 ? qo : ko);
    #pragma unroll
    for (int ni = 0; ni < 4; ni++) {
      int n = wc*64 + ni*16 + col;
      #pragma unroll
      for (int mi = 0; mi < 4; mi++) {
        int row = m0 + wr*64 + mi*16 + quad*4;
        #pragma unroll
        for (int r = 0; r < 4; r++)
          dst[(size_t)(row + r) * H_ + n] = f2bf(acc[mi][ni][r]);
      }
    }
  }
}

// ---------- kernel 4: causal flash, tile-PAIR per WG + 2-deep QK pipeline ----------
// R8 THEORY: rounds 0-7 were all insensitive to instruction-stream changes (removing
// ~500cyc of bpermute/plds: -8us; removing ~400cyc of QK chain: 0us) -> the per-
// iteration pole is the V access pattern shared by all of them: vT[128][4096] reads
// 8 fragments/wave at EXACT 128KB stride, each load = 16 rows x 64B scattered over
// 1MB (L1-thrashing, same-L2/L3-slice serialization). Fix: V stored TILED
// [g=key/32][128 dims][32 keys] -> per-iteration V tile is ONE contiguous 8KB block;
// each load instruction covers 1KB contiguous; waves 2-4 hit L1. Body otherwise
// byte-identical to R7 (pair, 112-reg-friendly, triple-buffer K, 2-deep QK pipeline).
#define CHUNK_ 512
__global__ __launch_bounds__(256, 2) void flash_kernel(const ushort* __restrict__ q,
    const ushort* __restrict__ k, const ushort* __restrict__ vT,
    float* __restrict__ Opart, float* __restrict__ ml) {
  const float SL2E = 0.08838834764831845f * 1.44269504088896340736f;
  int c = blockIdx.x;
  int tp = 31 - (int)blockIdx.y;              // heavy pairs first
  int b = blockIdx.z;
  if (tp < 4 * c) return;
  int tA = tp * 2, tB = tA + 1;
  int aA = tA >> 3, rA = tA & 7;
  int aB = tB >> 3, rB = tB & 7;
  int slotA = b * 288 + (aA + 1) * (4 * aA + rA) + c;
  int slotB = b * 288 + (aB + 1) * (4 * aB + rB) + c;

  int wave = threadIdx.x >> 6, lane = threadIdx.x & 63;
  int col = lane & 15, quad = lane >> 4;
  int q0A = tA * 64 + wave * 16;
  int q0B = q0A + 64;
  const ushort* qb = q + (size_t)b * S_ * H_;
  const ushort* kbp = k + (size_t)b * S_ * H_;
  const ushort* vb = vT + (size_t)b * S_ * H_;

  __shared__ ushort kl[3][32 * 128];          // TRIPLE buffer, XOR-swizzled 16B units

  bf16x8 qfA[4], qfB[4];
  {
    const ushort* qpA = qb + (size_t)(q0A + col) * H_ + quad * 8;
    const ushort* qpB = qb + (size_t)(q0B + col) * H_ + quad * 8;
    #pragma unroll
    for (int kc = 0; kc < 4; kc++) {
      qfA[kc] = *(const bf16x8*)(qpA + kc * 32);
      qfB[kc] = *(const bf16x8*)(qpB + kc * 32);
    }
  }

  f32x4 OA[8], OB[8];
  #pragma unroll
  for (int d = 0; d < 8; d++) { OA[d] = (f32x4){0.f,0.f,0.f,0.f}; OB[d] = (f32x4){0.f,0.f,0.f,0.f}; }
  float mA = -1e30f, lA = 0.f, mB = -1e30f, lB = 0.f;

  const int c0 = c * CHUNK_;
  const int kendWG = min(c0 + CHUNK_, tB * 64 + 64);
  const int nblk = (kendWG - c0 + 31) >> 5;   // >= 4 for active blocks
  const int qlimA = q0A + 15, qlimB = q0B + 15;

  const int sk0 = wave * 8 + quad;            // staged K rows sk0 and sk0+4
  const int gu0 = (col ^ (sk0 & 15)) * 8;     // pre-swizzled global src unit
  const int gu1 = (col ^ ((sk0 + 4) & 15)) * 8;
  const int lo0 = sk0 * 128 + col * 8;        // LDS offsets within a buffer
  const int lo1 = (sk0 + 4) * 128 + col * 8;

  // TILED V: tile g = c*16 + ib (8KB contiguous), element [h=col+d*16][ks=quad*8..]
  const ushort* vbase = vb + (size_t)c * 16 * 128 * 32 + col * 32 + quad * 8;

  uint4 a0, a1;
  { // prologue: stage block 0 directly to buf 0
    const ushort* kp = kbp + (size_t)(c0 + sk0) * H_;
    a0 = *(const uint4*)(kp + gu0);
    a1 = *(const uint4*)(kp + 4 * H_ + gu1);
    *(uint4*)(&kl[0][lo0]) = a0;
    *(uint4*)(&kl[0][lo1]) = a1;
  }
  if (nblk > 1) { // preload block 1 into regs
    const ushort* kp = kbp + (size_t)(c0 + 32 + sk0) * H_;
    a0 = *(const uint4*)(kp + gu0);
    a1 = *(const uint4*)(kp + 4 * H_ + gu1);
  }
  __syncthreads();

  // QK(0) -> current score state (kb=c0 <= qlimA always for active waves)
  f32x4 cB0, cB1, cA0, cA1;
  {
    const ushort* kcur = &kl[0][0];
    bf16x8 kf0[4], kf1[4];
    #pragma unroll
    for (int kc = 0; kc < 4; kc++) {
      int u = quad + kc * 4;
      kf0[kc] = *(const bf16x8*)(kcur + col*128        + ((u ^ col) * 8));
      kf1[kc] = *(const bf16x8*)(kcur + (16 + col)*128 + ((u ^ col) * 8));
    }
    cB0 = (f32x4){0.f,0.f,0.f,0.f}; cB1 = cB0; cA0 = cB0; cA1 = cB0;
    __builtin_amdgcn_s_setprio(1);
    #pragma unroll
    for (int kc = 0; kc < 4; kc++) {
      cB0 = __builtin_amdgcn_mfma_f32_16x16x32_bf16(kf0[kc], qfB[kc], cB0, 0, 0, 0);
      cB1 = __builtin_amdgcn_mfma_f32_16x16x32_bf16(kf1[kc], qfB[kc], cB1, 0, 0, 0);
      cA0 = __builtin_amdgcn_mfma_f32_16x16x32_bf16(kf0[kc], qfA[kc], cA0, 0, 0, 0);
      cA1 = __builtin_amdgcn_mfma_f32_16x16x32_bf16(kf1[kc], qfA[kc], cA1, 0, 0, 0);
    }
    __builtin_amdgcn_s_setprio(0);
  }

  int bw = 1;                                 // LDS buffer that receives K(ib+1)
  for (int ib = 0; ib < nblk; ib++) {
    const int kb0 = c0 + ib * 32;
    const int kb1 = kb0 + 32;
    if (ib + 1 < nblk) {                      // write K(ib+1) regs -> LDS buf bw
      *(uint4*)(&kl[bw][lo0]) = a0;
      *(uint4*)(&kl[bw][lo1]) = a1;
    }
    __syncthreads();
    if (ib + 2 < nblk) {                      // T14: load K(ib+2) regs
      const ushort* kp = kbp + (size_t)(kb0 + 64 + sk0) * H_;
      a0 = *(const uint4*)(kp + gu0);
      a1 = *(const uint4*)(kp + 4 * H_ + gu1);
    }
    // ---- QK(ib+1) -> next state (independent of softmax(ib)/PV(ib) below) ----
    f32x4 nB0 = (f32x4){0.f,0.f,0.f,0.f}, nB1 = nB0, nA0 = nB0, nA1 = nB0;
    if (ib + 1 < nblk && kb1 <= qlimB) {
      const ushort* kcur = &kl[bw][0];
      bf16x8 kf0[4], kf1[4];
      #pragma unroll
      for (int kc = 0; kc < 4; kc++) {
        int u = quad + kc * 4;
        kf0[kc] = *(const bf16x8*)(kcur + col*128        + ((u ^ col) * 8));
        kf1[kc] = *(const bf16x8*)(kcur + (16 + col)*128 + ((u ^ col) * 8));
      }
      __builtin_amdgcn_s_setprio(1);
      #pragma unroll
      for (int kc = 0; kc < 4; kc++) {
        nB0 = __builtin_amdgcn_mfma_f32_16x16x32_bf16(kf0[kc], qfB[kc], nB0, 0, 0, 0);
        nB1 = __builtin_amdgcn_mfma_f32_16x16x32_bf16(kf1[kc], qfB[kc], nB1, 0, 0, 0);
      }
      if (kb1 <= qlimA) {
        #pragma unroll
        for (int kc = 0; kc < 4; kc++) {
          nA0 = __builtin_amdgcn_mfma_f32_16x16x32_bf16(kf0[kc], qfA[kc], nA0, 0, 0, 0);
          nA1 = __builtin_amdgcn_mfma_f32_16x16x32_bf16(kf1[kc], qfA[kc], nA1, 0, 0, 0);
        }
      }
      __builtin_amdgcn_s_setprio(0);
    }
    // ---- iter ib: softmax + PV from current score state ----
    if (kb0 <= qlimB) {                       // wave-uniform
      const bool doA = (kb0 <= qlimA);
      bf16x8 vf03[4];
      #pragma unroll
      for (int j = 0; j < 4; j++)
        vf03[j] = *(const bf16x8*)(vbase + (size_t)ib * 4096 + j * 512);
      // ---- tile B softmax ----
      uint4 pfB4;
      {
        float s[8];
        #pragma unroll
        for (int r = 0; r < 4; r++) { s[r] = cB0[r]; s[4+r] = cB1[r]; }
        if (kb0 + 31 > q0B) {
          #pragma unroll
          for (int r = 0; r < 4; r++) {
            if (kb0 + quad*4 + r      > q0B + col) s[r]   = -1e30f;
            if (kb0 + 16 + quad*4 + r > q0B + col) s[4+r] = -1e30f;
          }
        }
        float cm = s[0];
        #pragma unroll
        for (int j = 1; j < 8; j++) cm = fmaxf(cm, s[j]);
        cm = red4max(cm);
        if (!__all(cm <= mB)) {               // T13 exact skip
          float mn = fmaxf(mB, cm);
          float alpha = exp2f((mB - mn) * SL2E);
          lB *= alpha;
          #pragma unroll
          for (int d = 0; d < 8; d++) OB[d] *= alpha;
          mB = mn;
        }
        float rs = 0.f;
        #pragma unroll
        for (int j = 0; j < 8; j++) { s[j] = exp2f((s[j] - mB) * SL2E); rs += s[j]; }
        lB += red4sum(rs);
        unsigned w0 = cvt_pk_bf16(s[0], s[1]);
        unsigned w1 = cvt_pk_bf16(s[2], s[3]);
        unsigned w2 = cvt_pk_bf16(s[4], s[5]);
        unsigned w3 = cvt_pk_bf16(s[6], s[7]);
        pl32sw(w0, w2); pl32sw(w1, w3);
        pl16sw(w0, w2); pl16sw(w1, w3);
        pfB4 = make_uint4(w0, w1, w2, w3);
      }
      bf16x8 vf47[4];                         // issue while softmaxA runs
      #pragma unroll
      for (int j = 0; j < 4; j++)
        vf47[j] = *(const bf16x8*)(vbase + (size_t)ib * 4096 + (4 + j) * 512);
      // ---- tile A softmax ----
      uint4 pfA4 = make_uint4(0u, 0u, 0u, 0u);
      if (doA) {
        float s[8];
        #pragma unroll
        for (int r = 0; r < 4; r++) { s[r] = cA0[r]; s[4+r] = cA1[r]; }
        if (kb0 + 31 > q0A) {
          #pragma unroll
          for (int r = 0; r < 4; r++) {
            if (kb0 + quad*4 + r      > q0A + col) s[r]   = -1e30f;
            if (kb0 + 16 + quad*4 + r > q0A + col) s[4+r] = -1e30f;
          }
        }
        float cm = s[0];
        #pragma unroll
        for (int j = 1; j < 8; j++) cm = fmaxf(cm, s[j]);
        cm = red4max(cm);
        if (!__all(cm <= mA)) {
          float mn = fmaxf(mA, cm);
          float alpha = exp2f((mA - mn) * SL2E);
          lA *= alpha;
          #pragma unroll
          for (int d = 0; d < 8; d++) OA[d] *= alpha;
          mA = mn;
        }
        float rs = 0.f;
        #pragma unroll
        for (int j = 0; j < 8; j++) { s[j] = exp2f((s[j] - mA) * SL2E); rs += s[j]; }
        lA += red4sum(rs);
        unsigned w0 = cvt_pk_bf16(s[0], s[1]);
        unsigned w1 = cvt_pk_bf16(s[2], s[3]);
        unsigned w2 = cvt_pk_bf16(s[4], s[5]);
        unsigned w3 = cvt_pk_bf16(s[6], s[7]);
        pl32sw(w0, w2); pl32sw(w1, w3);
        pl16sw(w0, w2); pl16sw(w1, w3);
        pfA4 = make_uint4(w0, w1, w2, w3);
      }
      // ---- PV for both tiles (shared vf) ----
      {
        union { uint4 u4; bf16x8 v; } puB, puA;
        puB.u4 = pfB4; puA.u4 = pfA4;
        __builtin_amdgcn_s_setprio(1);
        #pragma unroll
        for (int j = 0; j < 4; j++)
          OB[j] = __builtin_amdgcn_mfma_f32_16x16x32_bf16(vf03[j], puB.v, OB[j], 0, 0, 0);
        if (doA) {
          #pragma unroll
          for (int j = 0; j < 4; j++)
            OA[j] = __builtin_amdgcn_mfma_f32_16x16x32_bf16(vf03[j], puA.v, OA[j], 0, 0, 0);
        }
        #pragma unroll
        for (int j = 0; j < 4; j++)
          OB[4 + j] = __builtin_amdgcn_mfma_f32_16x16x32_bf16(vf47[j], puB.v, OB[4 + j], 0, 0, 0);
        if (doA) {
          #pragma unroll
          for (int j = 0; j < 4; j++)
            OA[4 + j] = __builtin_amdgcn_mfma_f32_16x16x32_bf16(vf47[j], puA.v, OA[4 + j], 0, 0, 0);
        }
        __builtin_amdgcn_s_setprio(0);
      }
    }
    // rotate pipeline state (static names, no dynamic indexing)
    cB0 = nB0; cB1 = nB1; cA0 = nA0; cA1 = nA1;
    bw++; if (bw == 3) bw = 0;
  }

  float* OpA = Opart + (size_t)slotA * (64 * 128) + (size_t)(wave*16 + col) * 128 + quad * 4;
  float* OpB = Opart + (size_t)slotB * (64 * 128) + (size_t)(wave*16 + col) * 128 + quad * 4;
  #pragma unroll
  for (int d = 0; d < 8; d++) {
    *(f32x4*)(OpA + d * 16) = OA[d];
    *(f32x4*)(OpB + d * 16) = OB[d];
  }
  if (quad == 0) {
    *(float2*)(ml + (size_t)slotA * 128 + (size_t)(wave*16 + col) * 2) = make_float2(mA, lA);
    *(float2*)(ml + (size_t)slotB * 128 + (size_t)(wave*16 + col) * 2) = make_float2(mB, lB);
  }
}

// ---------- kernel 5: combine split-K partials ----------
__global__ __launch_bounds__(256) void combine_kernel(const float* __restrict__ Opart,
    const float* __restrict__ ml, float* __restrict__ out) {
  const float SL2E = 0.08838834764831845f * 1.44269504088896340736f;
  int tile = blockIdx.x, b = blockIdx.y;
  int a = tile >> 3, rr = tile & 7;
  int nc = a + 1;
  int base = b * 288 + (a + 1) * (4 * a + rr);
  int tid = threadIdx.x;
  int row = tid >> 2;
  int cs = (tid & 3) * 4;
  float m_c[8], l_c[8];
  float mstar = -1e30f;
  for (int ci = 0; ci < nc; ci++) {
    m_c[ci] = ml[(size_t)(base + ci) * 128 + row * 2];
    l_c[ci] = ml[(size_t)(base + ci) * 128 + row * 2 + 1];
    mstar = fmaxf(mstar, m_c[ci]);
  }
  float denom = 0.f;
  float w_c[8];
  for (int ci = 0; ci < nc; ci++) {
    w_c[ci] = exp2f((m_c[ci] - mstar) * SL2E);
    denom += w_c[ci] * l_c[ci];
  }
  float inv = 1.f / denom;
  f32x4 acc[8];
  #pragma unroll
  for (int i = 0; i < 8; i++) acc[i] = (f32x4){0.f,0.f,0.f,0.f};
  for (int ci = 0; ci < nc; ci++) {
    const float* Op = Opart + (size_t)(base + ci) * (64 * 128) + row * 128;
    float w = w_c[ci];
    #pragma unroll
    for (int i = 0; i < 8; i++) {
      f32x4 v = *(const f32x4*)(Op + cs + i * 16);
      acc[i] += w * v;
    }
  }
  float* o = out + ((size_t)(b * S_) + tile * 64 + row) * H_;
  #pragma unroll
  for (int i = 0; i < 8; i++) {
    f32x4 v = acc[i] * inv;
    *(f32x4*)(o + cs + i * 16) = v;
  }
}

extern "C" void kernel_launch(void* const* d_in, const int* in_sizes, int n_in,
                              void* d_out, int out_size, void* d_ws, size_t ws_size,
                              hipStream_t stream) {
  (void)in_sizes; (void)n_in; (void)out_size; (void)ws_size;
  const float* x  = (const float*)d_in[0];
  const float* Wq = (const float*)d_in[1];
  const float* Wk = (const float*)d_in[2];
  const float* Wv = (const float*)d_in[3];
  float* out = (float*)d_out;
  char* ws = (char*)d_ws;
  ushort* Wt = (ushort*)ws;                                        // 768 KB
  ushort* qb = (ushort*)(ws + 786432);                             // 4 MB each
  ushort* kb = qb + (size_t)M_ * H_;
  ushort* vT = kb + (size_t)M_ * H_;
  float* Opart = (float*)(ws + 786432 + 3 * (size_t)M_ * H_ * 2);  // 36 MB
  float* ml = Opart + (size_t)1152 * 64 * 128;                     // 0.6 MB
  ushort* xbuf = (ushort*)Opart;   // alias: xb dead before flash writes Opart

  hipLaunchKernelGGL(wt_kernel,   dim3(384), dim3(256), 0, stream, Wq, Wk, Wv, Wt);
  hipLaunchKernelGGL(xb_kernel,   dim3(8192), dim3(256), 0, stream, x, xbuf);
  hipLaunchKernelGGL(qkv_gemm,    dim3(128, 3), dim3(256), 0, stream, xbuf, Wt, qb, kb, vT);
  hipLaunchKernelGGL(flash_kernel,dim3(8, 32, 4), dim3(256), 0, stream, qb, kb, vT, Opart, ml);
  hipLaunchKernelGGL(combine_kernel, dim3(64, 4), dim3(256), 0, stream, Opart, ml, out);
}